// Round 11
// baseline (1555.521 us; speedup 1.0000x reference)
//
#include <hip/hip_runtime.h>
#include <hip/hip_bf16.h>
#include <math.h>

#define BB 32
#define TT 128
#define TD 127
#define EMB 256
#define HID 512
#define G4 2048
#define NV 10000
#define NB 64        // lstm blocks
#define NWK 192      // worker blocks
#define GRID_UBER (NB + NWK)
#define UPB 8
#define NT_STEPS (TT + TD)
#define CAND_CAP 16
#define CAND_DELTA 1.0f

#define NJOB_DEC 512
#define NJOB_TR  313
#define NJOB_WN  20
#define NJOB_RM  4096
#define NJOBS (NJOB_DEC + NJOB_TR + NJOB_WN + NJOB_RM)

typedef __attribute__((ext_vector_type(8))) short short8v;
typedef __attribute__((ext_vector_type(4))) float f32x4;

__device__ __forceinline__ unsigned short bf16_rne(float x){
    unsigned int u = __float_as_uint(x);
    u += 0x7fffu + ((u >> 16) & 1u);
    return (unsigned short)(u >> 16);
}
__device__ __forceinline__ float bf16f(unsigned short h){
    return __uint_as_float(((unsigned int)h) << 16);
}

// ---------------- GEMM (encoder X): X[t][col][b] = embed[tok] @ W + bias ----
__global__ __launch_bounds__(256) void gemm_x(const int* __restrict__ ids,
        const float* __restrict__ embed, const float* __restrict__ W,
        const float* __restrict__ bias, float* __restrict__ X, int M)
{
    __shared__ float As[16][128];
    __shared__ float Bs[16][128];
    __shared__ int toks[128];
    const int tid = threadIdx.x;
    const int m0 = blockIdx.y * 128, n0 = blockIdx.x * 128;
    if (tid < 128) {
        int mr = m0 + tid, tk = 0;
        if (mr < M) { int t = mr >> 5, b = mr & 31; tk = ids[b*TT + t]; }
        toks[tid] = tk;
    }
    __syncthreads();
    float acc[8][8] = {};
    const int ty = tid >> 4, tx = tid & 15;
    for (int kt = 0; kt < EMB; kt += 16) {
        #pragma unroll
        for (int i = 0; i < 2; i++) {
            int idx = tid*2 + i;
            int row = idx >> 2, k4 = (idx & 3)*4;
            float4 a = *(const float4*)&embed[(size_t)toks[row]*EMB + kt + k4];
            As[k4+0][row] = a.x; As[k4+1][row] = a.y; As[k4+2][row] = a.z; As[k4+3][row] = a.w;
        }
        #pragma unroll
        for (int i = 0; i < 2; i++) {
            int idx = tid*2 + i;
            int kr = idx >> 5, c4 = (idx & 31)*4;
            *(float4*)&Bs[kr][c4] = *(const float4*)&W[(size_t)(kt+kr)*G4 + n0 + c4];
        }
        __syncthreads();
        #pragma unroll
        for (int k = 0; k < 16; k++) {
            float a8[8], b8[8];
            #pragma unroll
            for (int i = 0; i < 8; i++) a8[i] = As[k][ty*8+i];
            #pragma unroll
            for (int j = 0; j < 8; j++) b8[j] = Bs[k][tx*8+j];
            #pragma unroll
            for (int i = 0; i < 8; i++) {
                #pragma unroll
                for (int j = 0; j < 8; j++)
                    acc[i][j] = fmaf(a8[i], b8[j], acc[i][j]);
            }
        }
        __syncthreads();
    }
    #pragma unroll
    for (int i = 0; i < 8; i++) {
        int mr = m0 + ty*8 + i;
        if (mr < M) {
            int tt = mr >> 5, bb2 = mr & 31;
            #pragma unroll
            for (int j = 0; j < 8; j++) {
                int nc = n0 + tx*8 + j;
                X[((size_t)tt*G4 + nc)*BB + bb2] = acc[i][j] + bias[nc];
            }
        }
    }
}

// ---------------- UBER kernel: 64 LSTM blocks (role-split step) + 192 workers
__global__ __launch_bounds__(512) void lstm_persist(
        const float* __restrict__ Xenc, float* __restrict__ Xdec,
        const float* __restrict__ Whh_e, const float* __restrict__ Whh_d,
        unsigned int* __restrict__ h_pk,   // [2][512][32]
        float* __restrict__ hs,            // [127][32][512]
        int* __restrict__ flags,           // [64]
        int* __restrict__ decdone,         // [1]
        const int* __restrict__ ids, const float* __restrict__ dEmb,
        const float* __restrict__ dWih, const float* __restrict__ dB,
        const float* __restrict__ fcW, float* __restrict__ fcWt,
        const float* __restrict__ fcb, const int* __restrict__ mask,
        const float* __restrict__ gum, const float* __restrict__ rinit,
        float* __restrict__ Mr, unsigned int* __restrict__ scal,
        int* __restrict__ candCnt, int* __restrict__ candList,
        float* __restrict__ outp)
{
    __shared__ float smem[11392];
    __shared__ int gdone;                  // monotonic gate-wave join counter
    const int tid = threadIdx.x;
    const int bid = blockIdx.x;

    if (bid >= NB) {
        // =============== worker blocks: grid-stride job loop ===============
        const int wid = bid - NB;
        for (int job = wid; job < NJOBS; job += NWK) {
            if (job < NJOB_DEC) {
                // ---- decoder-X gemm tile (128m x 128n), 512 threads ----
                const int my = job >> 4, nx = job & 15;
                const int m0 = my*128, n0 = nx*128;
                const int M = TD*BB;
                float* As = smem;              // [16][128]
                float* Bs = smem + 2048;       // [16][128]
                int* toks = (int*)(smem + 4096);
                if (tid < 128) {
                    int mr = m0 + tid, tk = 0;
                    if (mr < M) { int t = mr >> 5, b2 = mr & 31; tk = ids[b2*TT + t]; }
                    toks[tid] = tk;
                }
                __syncthreads();
                float acc[4][8] = {};
                const int ty = tid >> 4, tx = tid & 15;
                for (int kt = 0; kt < EMB; kt += 16) {
                    {
                        int row = tid >> 2, k4 = (tid & 3)*4;
                        float4 a = *(const float4*)&dEmb[(size_t)toks[row]*EMB + kt + k4];
                        As[(k4+0)*128+row] = a.x; As[(k4+1)*128+row] = a.y;
                        As[(k4+2)*128+row] = a.z; As[(k4+3)*128+row] = a.w;
                    }
                    {
                        int kr = tid >> 5, c4 = (tid & 31)*4;
                        *(float4*)&Bs[kr*128 + c4] =
                            *(const float4*)&dWih[(size_t)(kt+kr)*G4 + n0 + c4];
                    }
                    __syncthreads();
                    #pragma unroll
                    for (int k = 0; k < 16; k++) {
                        float a4[4], b8[8];
                        #pragma unroll
                        for (int i = 0; i < 4; i++) a4[i] = As[k*128 + ty*4+i];
                        #pragma unroll
                        for (int j = 0; j < 8; j++) b8[j] = Bs[k*128 + tx*8+j];
                        #pragma unroll
                        for (int i = 0; i < 4; i++) {
                            #pragma unroll
                            for (int j = 0; j < 8; j++)
                                acc[i][j] = fmaf(a4[i], b8[j], acc[i][j]);
                        }
                    }
                    __syncthreads();
                }
                #pragma unroll
                for (int i = 0; i < 4; i++) {
                    int mr = m0 + ty*4 + i;
                    if (mr < M) {
                        int t = mr >> 5, b2 = mr & 31;
                        #pragma unroll
                        for (int j = 0; j < 8; j++) {
                            int nc = n0 + tx*8 + j;
                            Xdec[((size_t)t*G4 + nc)*BB + b2] = acc[i][j] + dB[nc];
                        }
                    }
                }
                __syncthreads();               // all stores acked
                if (tid == 0)                  // release: wbl2 + count
                    __hip_atomic_fetch_add(decdone, 1,
                        __ATOMIC_RELEASE, __HIP_MEMORY_SCOPE_AGENT);
            } else if (job < NJOB_DEC + NJOB_TR) {
                // ---- fc_W transpose strip: 32 v-cols x 512 k ----
                const int v0 = (job - NJOB_DEC)*32;
                float* tile = smem;            // [16][33]
                for (int k0 = 0; k0 < HID; k0 += 16) {
                    {
                        int kk = tid >> 5, vv = tid & 31;
                        int v = v0 + vv;
                        tile[kk*33 + vv] = (v < NV) ? fcW[(size_t)(k0+kk)*NV + v] : 0.f;
                    }
                    __syncthreads();
                    {
                        int vy = tid >> 4, kx = tid & 15;
                        int v = v0 + vy;
                        if (v < NV) fcWt[(size_t)v*HID + k0 + kx] = tile[kx*33 + vy];
                    }
                    __syncthreads();
                }
            } else if (job < NJOB_DEC + NJOB_TR + NJOB_WN) {
                // ---- wnorm: 512 vocab cols ----
                int v = (job - NJOB_DEC - NJOB_TR)*512 + tid;
                if (v < NV) {
                    float s = 0.f;
                    for (int k = 0; k < HID; k++) {
                        float x = fcW[(size_t)k*NV + v]; s = fmaf(x, x, s);
                    }
                    atomicMax(&scal[0], __float_as_uint(s));
                    atomicMax(&scal[1], __float_as_uint(fabsf(fcb[v])));
                }
            } else {
                // ---- row job: finalize easy rows; Mr+candidates+zero for rest
                const int row = job - NJOB_DEC - NJOB_TR - NJOB_WN;
                const int b = row >> 7, t = row & 127;
                const int mrow = mask[row];
                float4* o = (float4*)(outp + (size_t)row*NV);
                if (mrow == 0) {
                    int win = ids[b*TT + t];
                    for (int idx = tid; idx < 2500; idx += 512) {
                        int vb = idx*4;
                        float4 val = {0.f,0.f,0.f,0.f};
                        if (win >= vb && win < vb+4) ((float*)&val)[win-vb] = 1.0f;
                        o[idx] = val;
                    }
                } else if (t == 0) {
                    const float* g  = gum   + (size_t)b*NV;
                    const float* r0 = rinit + (size_t)b*NV;
                    float bs = -1e30f; int bv = 0x7fffffff;
                    for (int v = tid; v < NV; v += 512) {
                        float sc = r0[v] + g[v];
                        if (sc > bs || (sc == bs && v < bv)) { bs = sc; bv = v; }
                    }
                    float* red = smem;
                    int* idxr = (int*)(smem + 512);
                    red[tid] = bs; idxr[tid] = bv; __syncthreads();
                    for (int s = 256; s; s >>= 1) {
                        if (tid < s) {
                            if (red[tid+s] > red[tid] ||
                                (red[tid+s] == red[tid] && idxr[tid+s] < idxr[tid])) {
                                red[tid] = red[tid+s]; idxr[tid] = idxr[tid+s];
                            }
                        }
                        __syncthreads();
                    }
                    int win = idxr[0];
                    __syncthreads();
                    for (int idx = tid; idx < 2500; idx += 512) {
                        int vb = idx*4;
                        float4 val = {0.f,0.f,0.f,0.f};
                        if (win >= vb && win < vb+4) ((float*)&val)[win-vb] = 1.0f;
                        o[idx] = val;
                    }
                } else {
                    int* wk   = (int*)&smem[1024];
                    int* ccnt = (int*)&smem[1040];
                    int mi = (tid < TT) ? mask[b*TT + tid] : 0;
                    unsigned long long bal = __ballot(tid < t && mi != 0);
                    if ((tid & 63) == 0) wk[tid >> 6] = __popcll(bal);
                    if (tid == 0) *ccnt = 0;
                    __syncthreads();
                    const int k = wk[0] + wk[1];
                    const float* g = gum + ((size_t)k*BB + b)*NV;
                    float m = -1e30f;
                    for (int v = tid; v < NV; v += 512) m = fmaxf(m, g[v]);
                    float* red = smem;
                    red[tid] = m; __syncthreads();
                    for (int s = 256; s; s >>= 1) {
                        if (tid < s) red[tid] = fmaxf(red[tid], red[tid+s]);
                        __syncthreads();
                    }
                    const float Mv = red[0];
                    const float thr0 = Mv - CAND_DELTA;
                    for (int v = tid; v < NV; v += 512) {
                        if (g[v] >= thr0) {
                            int pos = atomicAdd(ccnt, 1);
                            if (pos < CAND_CAP) candList[row*CAND_CAP + pos] = v;
                        }
                    }
                    float4 z = {0.f,0.f,0.f,0.f};
                    for (int idx = tid; idx < 2500; idx += 512) o[idx] = z;
                    __syncthreads();
                    if (tid == 0) { candCnt[row] = *ccnt; Mr[row] = Mv; }
                    __syncthreads();
                }
            }
        }
        return;
    }

    // =============== LSTM path: r5 exchange fabric, role-split schedule ======
    // wave 0: pure poller (clean vmcnt). waves 1-4: gates. waves 5-7: X stage.
    float* partials = smem;            // [8][32][36] (also W-stage scratch)
    float* xbuf     = smem + 9216;     // [2][32][33]

    const int u0  = bid*UPB;
    const int w   = tid >> 6;
    const int l   = tid & 63;
    const int rl  = l & 15;
    const int kg  = (l >> 4) * 8;
    const int r4  = (l >> 4) * 4;
    const int gtid = tid - 64;                 // gate index for waves 1-4
    const int gb  = gtid >> 3, gul = gtid & 7;

    short8v wH_n0k0, wH_n0k1, wH_n1k0, wH_n1k1;
    short8v wL_n0k0, wL_n0k1, wL_n1k0, wL_n1k1;

    #define BW(WH, WL, KB, CO) do { _Pragma("unroll") \
        for (int j = 0; j < 8; ++j) { \
            float wv2 = partials[((KB)+j)*32 + (CO) + rl]; \
            unsigned short htop = bf16_rne(wv2); \
            WH[j] = (short)htop; \
            WL[j] = (short)bf16_rne(wv2 - bf16f(htop)); \
        } } while(0)

    #define STAGE_BUILD(SRC) do { \
        for (int c = 0; c < 4; ++c) { \
            int k0 = c*128; \
            __syncthreads(); \
            for (int i = tid; i < 4096; i += 512) { \
                int kl = i >> 5, n = i & 31; \
                partials[kl*32 + n] = SRC[(size_t)(k0+kl)*G4 + (size_t)((n>>3)*512 + u0 + (n&7))]; \
            } \
            __syncthreads(); \
            if ((w >> 1) == c) { \
                int kb0 = w*64 - k0 + kg; \
                BW(wH_n0k0, wL_n0k0, kb0,      0); \
                BW(wH_n0k1, wL_n0k1, kb0 + 32, 0); \
                BW(wH_n1k0, wL_n1k0, kb0,     16); \
                BW(wH_n1k1, wL_n1k1, kb0 + 32,16); \
            } \
        } \
        __syncthreads(); } while(0)

    STAGE_BUILD(Whh_e);

    {   // prologue: stage X(0) into xbuf[0]; init gdone
        if (tid == 0) gdone = 0;
        for (int i = tid; i < 1024; i += 512) {
            int row2 = i & 31, n = i >> 5;
            xbuf[row2*33 + n] = Xenc[(size_t)((n>>3)*512 + u0 + (n&7))*32 + row2];
        }
        __syncthreads();
    }

    float c_reg = 0.f;

    #define MM6(ACC, AH0, AH1, AL0, AL1, WH0, WH1, WL0, WL1) do { \
        ACC = __builtin_amdgcn_mfma_f32_16x16x32_bf16(AH0, WH0, ACC, 0,0,0); \
        ACC = __builtin_amdgcn_mfma_f32_16x16x32_bf16(AH1, WH1, ACC, 0,0,0); \
        ACC = __builtin_amdgcn_mfma_f32_16x16x32_bf16(AL0, WH0, ACC, 0,0,0); \
        ACC = __builtin_amdgcn_mfma_f32_16x16x32_bf16(AL1, WH1, ACC, 0,0,0); \
        ACC = __builtin_amdgcn_mfma_f32_16x16x32_bf16(AH0, WL0, ACC, 0,0,0); \
        ACC = __builtin_amdgcn_mfma_f32_16x16x32_bf16(AH1, WL1, ACC, 0,0,0); \
    } while(0)

    for (int gstep = 0; gstep < NT_STEPS; ++gstep) {
        const bool enc = gstep < TT;
        const bool last = (gstep == NT_STEPS - 1);
        if (gstep == TT) STAGE_BUILD(Whh_d);   // phase switch (all waves, loop top)

        // ---- MFMA phase (all 8 waves) ----
        f32x4 acc00 = {0,0,0,0}, acc01 = {0,0,0,0}, acc10 = {0,0,0,0}, acc11 = {0,0,0,0};
        if (gstep > 0) {
            const unsigned int* hp = h_pk + (size_t)(gstep & 1)*16384;
            short8v aH_m0k0, aH_m0k1, aH_m1k0, aH_m1k1;
            short8v aL_m0k0, aL_m0k1, aL_m1k0, aL_m1k1;
            #define LOAD_A(AH, AL, MT, KS) do { \
                unsigned int pv[8]; \
                int kbase = w*64 + (KS)*32 + kg; \
                int brow = (MT)*16 + rl; \
                _Pragma("unroll") \
                for (int j = 0; j < 8; ++j) \
                    pv[j] = __hip_atomic_load(&hp[(kbase+j)*32 + brow], \
                                __ATOMIC_RELAXED, __HIP_MEMORY_SCOPE_AGENT); \
                _Pragma("unroll") \
                for (int j = 0; j < 8; ++j) { \
                    AH[j] = (short)(pv[j] & 0xffffu); \
                    AL[j] = (short)(pv[j] >> 16); \
                } } while(0)
            LOAD_A(aH_m0k0, aL_m0k0, 0, 0); LOAD_A(aH_m0k1, aL_m0k1, 0, 1);
            LOAD_A(aH_m1k0, aL_m1k0, 1, 0); LOAD_A(aH_m1k1, aL_m1k1, 1, 1);
            MM6(acc00, aH_m0k0, aH_m0k1, aL_m0k0, aL_m0k1, wH_n0k0, wH_n0k1, wL_n0k0, wL_n0k1);
            MM6(acc01, aH_m0k0, aH_m0k1, aL_m0k0, aL_m0k1, wH_n1k0, wH_n1k1, wL_n1k0, wL_n1k1);
            MM6(acc10, aH_m1k0, aH_m1k1, aL_m1k0, aL_m1k1, wH_n0k0, wH_n0k1, wL_n0k0, wL_n0k1);
            MM6(acc11, aH_m1k0, aH_m1k1, aL_m1k0, aL_m1k1, wH_n1k0, wH_n1k1, wL_n1k0, wL_n1k1);
        }
        #pragma unroll
        for (int j = 0; j < 4; ++j) {
            partials[(w*32 +      r4 + j)*36 +      rl] = acc00[j];
            partials[(w*32 +      r4 + j)*36 + 16 + rl] = acc01[j];
            partials[(w*32 + 16 + r4 + j)*36 +      rl] = acc10[j];
            partials[(w*32 + 16 + r4 + j)*36 + 16 + rl] = acc11[j];
        }
        // ---- sync #1: partials ready ----
        asm volatile("s_waitcnt lgkmcnt(0)" ::: "memory");
        __builtin_amdgcn_s_barrier();

        if (w >= 1 && w <= 4) {
            // ---- gate waves: gates, h stores, drain, join, flag (wave 1) ----
            float pre[4];
            #pragma unroll
            for (int gg = 0; gg < 4; ++gg) {
                float s = xbuf[(gstep & 1)*1056 + gb*33 + gg*8 + gul];
                #pragma unroll
                for (int ww = 0; ww < 8; ++ww)
                    s += partials[(ww*32 + gb)*36 + gg*8 + gul];
                pre[gg] = s;
            }
            float iv = 1.f/(1.f + expf(-pre[0]));
            float fv = 1.f/(1.f + expf(-pre[1]));
            float gv = tanhf(pre[2]);
            float ov = 1.f/(1.f + expf(-pre[3]));
            c_reg = fmaf(fv, c_reg, iv*gv);
            float hv = ov * tanhf(c_reg);
            unsigned short hh = bf16_rne(hv);
            unsigned short hl = bf16_rne(hv - bf16f(hh));
            unsigned int pk = (unsigned int)hh | ((unsigned int)hl << 16);
            if (!enc) hs[((size_t)(gstep-TT)*BB + gb)*HID + u0 + gul] = hv;
            __hip_atomic_store(&h_pk[(size_t)((gstep+1) & 1)*16384 + (u0+gul)*32 + gb],
                               pk, __ATOMIC_RELAXED, __HIP_MEMORY_SCOPE_AGENT);
            asm volatile("s_waitcnt vmcnt(0)" ::: "memory");  // drain hs + h_pk
            if (!last) {
                if (l == 0) atomicAdd(&gdone, 1);
                if (w == 1) {
                    int tgt = 4*(gstep + 1);
                    while (*(volatile int*)&gdone < tgt) {}
                    if (l == 0)
                        __hip_atomic_store(&flags[bid], gstep + 1,
                                           __ATOMIC_RELAXED, __HIP_MEMORY_SCOPE_AGENT);
                }
            }
        } else if (w == 0) {
            // ---- poll wave: clean vmcnt, overlapped with gates ----
            if (!last) {
                while (true) {
                    int f = __hip_atomic_load(&flags[l], __ATOMIC_RELAXED,
                                              __HIP_MEMORY_SCOPE_AGENT);
                    if (__ballot(f <= gstep) == 0ull) break;
                }
            }
        } else {
            // ---- staging waves 5-7: X(g+1) -> xbuf[(g+1)&1] ----
            if (!last) {
                if (gstep + 1 == TT) {         // one-time decoder-X readiness
                    while (__hip_atomic_load(decdone, __ATOMIC_RELAXED,
                                             __HIP_MEMORY_SCOPE_AGENT) < NJOB_DEC)
                        __builtin_amdgcn_s_sleep(8);
                    __builtin_amdgcn_fence(__ATOMIC_ACQUIRE, "agent");
                }
                int tn = gstep + 1 < TT ? gstep + 1 : gstep + 1 - TT;
                const float* Xt = (gstep + 1 < TT ? Xenc : (const float*)Xdec)
                                  + (size_t)tn*G4*BB;
                for (int i = tid - 320; i < 1024; i += 192) {
                    int row2 = i & 31, n = i >> 5;
                    xbuf[((gstep+1) & 1)*1056 + row2*33 + n] =
                        Xt[(size_t)((n>>3)*512 + u0 + (n&7))*32 + row2];
                }
            }
        }
        // ---- sync #2 ----
        asm volatile("s_waitcnt lgkmcnt(0)" ::: "memory");
        __builtin_amdgcn_s_barrier();
        asm volatile("" ::: "memory");
    }
}

// ------- final: masked t>=1 rows only; candidate dots + single-elem write ----
__global__ __launch_bounds__(256) void cand_write(
        const int* __restrict__ mask, const float* __restrict__ gum,
        const float* __restrict__ hs, const float* __restrict__ Wt,
        const float* __restrict__ fcb, const float* __restrict__ Mr,
        const unsigned int* __restrict__ scal,
        const int* __restrict__ candCnt, const int* __restrict__ candList,
        float* __restrict__ out)
{
    const int row = blockIdx.x, b = row >> 7, t = row & 127;
    if (t == 0 || mask[row] == 0) return;      // handled inside uber kernel
    const int tid = threadIdx.x;
    __shared__ float red[256];
    __shared__ int list[256];
    __shared__ int wcnt[4];

    int mi = (tid < TT) ? mask[b*TT + tid] : 0;
    unsigned long long bal = __ballot(tid < t && mi != 0);
    if ((tid & 63) == 0) wcnt[tid >> 6] = __popcll(bal);
    __syncthreads();
    const int k = wcnt[0] + wcnt[1];
    __syncthreads();

    const float* g    = gum + ((size_t)k*BB + b)*NV;
    const float* hrow = hs + ((size_t)(t-1)*BB + b)*HID;
    float hn = 0.f;
    for (int k2 = tid; k2 < HID; k2 += 256) { float x = hrow[k2]; hn = fmaf(x, x, hn); }
    red[tid] = hn; __syncthreads();
    for (int s = 128; s; s >>= 1) {
        if (tid < s) red[tid] += red[tid+s];
        __syncthreads();
    }
    const float Mv = Mr[row];
    float bound = sqrtf(__uint_as_float(scal[0])) * sqrtf(red[0])
                + __uint_as_float(scal[1]);
    float thr = Mv - 2.0f*bound*1.05f - 1e-6f;
    __syncthreads();

    float curS = -1e30f; int curV = 0x7fffffff;
    const int cnt = candCnt[row];

    if (cnt <= CAND_CAP && thr >= Mv - CAND_DELTA) {
        for (int ci = 0; ci < cnt; ci++) {
            int vc = candList[row*CAND_CAP + ci];
            float p = 0.f;
            for (int k2 = tid; k2 < HID; k2 += 256)
                p = fmaf(hrow[k2], Wt[(size_t)vc*HID + k2], p);
            red[tid] = p; __syncthreads();
            for (int s = 128; s; s >>= 1) {
                if (tid < s) red[tid] += red[tid+s];
                __syncthreads();
            }
            if (tid == 0) {
                float sc = (red[0] + fcb[vc]) + g[vc];
                if (sc > curS || (sc == curS && vc < curV)) { curS = sc; curV = vc; }
            }
            __syncthreads();
        }
    } else {
        int wv = tid >> 6, lane = tid & 63;
        for (int v0 = 0; v0 < NV; v0 += 256) {
            int v = v0 + tid;
            bool ok = (v < NV) && (g[v] >= thr);
            unsigned long long mb = __ballot(ok);
            if (lane == 0) wcnt[wv] = __popcll(mb);
            __syncthreads();
            int off = 0;
            #pragma unroll
            for (int w = 0; w < 4; w++) if (w < wv) off += wcnt[w];
            int tot = wcnt[0] + wcnt[1] + wcnt[2] + wcnt[3];
            if (ok) {
                int pos = off + __popcll(mb & ((1ull << lane) - 1ull));
                list[pos] = v;
            }
            __syncthreads();
            for (int ci = 0; ci < tot; ci++) {
                int vc = list[ci];
                float p = 0.f;
                for (int k2 = tid; k2 < HID; k2 += 256)
                    p = fmaf(hrow[k2], Wt[(size_t)vc*HID + k2], p);
                red[tid] = p; __syncthreads();
                for (int s = 128; s; s >>= 1) {
                    if (tid < s) red[tid] += red[tid+s];
                    __syncthreads();
                }
                if (tid == 0) {
                    float sc = (red[0] + fcb[vc]) + g[vc];
                    if (sc > curS || (sc == curS && vc < curV)) { curS = sc; curV = vc; }
                }
                __syncthreads();
            }
        }
    }
    if (tid == 0) out[(size_t)row*NV + curV] = 1.0f;   // row pre-zeroed in uber
}

extern "C" void kernel_launch(void* const* d_in, const int* in_sizes, int n_in,
                              void* d_out, int out_size, void* d_ws, size_t ws_size,
                              hipStream_t stream)
{
    const int*   ids   = (const int*)d_in[0];
    const int*   mask  = (const int*)d_in[1];
    const float* eEmb  = (const float*)d_in[2];
    const float* eWih  = (const float*)d_in[3];
    const float* eWhh  = (const float*)d_in[4];
    const float* eB    = (const float*)d_in[5];
    const float* dEmb  = (const float*)d_in[6];
    const float* dWih  = (const float*)d_in[7];
    const float* dWhh  = (const float*)d_in[8];
    const float* dB    = (const float*)d_in[9];
    const float* fcW   = (const float*)d_in[10];
    const float* fcb   = (const float*)d_in[11];
    const float* rinit = (const float*)d_in[12];
    const float* gum   = (const float*)d_in[13];
    float* out = (float*)d_out;

    float* wsf = (float*)d_ws;
    size_t off = 0;
    float* Xenc = wsf + off; off += (size_t)TT*BB*G4;        // [t][col][b]
    float* Xdec = wsf + off; off += (size_t)TD*BB*G4;
    unsigned int* h_pk = (unsigned int*)(wsf + off); off += 2*(size_t)BB*HID;
    float* hs   = wsf + off; off += (size_t)TD*BB*HID;
    float* fcWt = wsf + off; off += (size_t)NV*HID;
    float* Mr   = wsf + off; off += 4096;
    int* candCnt  = (int*)(wsf + off); off += 4096;
    int* candList = (int*)(wsf + off); off += 4096*CAND_CAP;
    unsigned int* ctl = (unsigned int*)(wsf + off); off += 128;
    unsigned int* scal = ctl;                 // [0..7]
    int* flags   = (int*)(ctl + 8);           // [8..71]
    int* decdone = (int*)(ctl + 72);          // [72]

    hipMemsetAsync(ctl, 0, 128*sizeof(int), stream);

    dim3 gblk(16, 32);
    gemm_x<<<gblk, 256, 0, stream>>>(ids, eEmb, eWih, eB, Xenc, TT*BB);

    lstm_persist<<<GRID_UBER, 512, 0, stream>>>(Xenc, Xdec, eWhh, dWhh,
        h_pk, hs, flags, decdone,
        ids, dEmb, dWih, dB, fcW, fcWt, fcb, mask, gum, rinit,
        Mr, scal, candCnt, candList, out);

    cand_write<<<4096, 256, 0, stream>>>(mask, gum, hs, fcWt, fcb,
                                         Mr, scal, candCnt, candList, out);
}

// Round 12
// 1023.369 us; speedup vs baseline: 1.5200x; 1.5200x over previous
//
#include <hip/hip_runtime.h>
#include <hip/hip_bf16.h>
#include <math.h>

#define BB 32
#define TT 128
#define TD 127
#define EMB 256
#define HID 512
#define G4 2048
#define NV 10000
#define NB 64        // lstm blocks
#define NWK 192      // worker blocks
#define GRID_UBER (NB + NWK)
#define UPB 8
#define NT_STEPS (TT + TD)
#define CAND_CAP 16
#define CAND_DELTA 1.0f

#define NJOB_ENC 512
#define NJOB_DEC 512
#define NJOB_TR  313
#define NJOB_WN  20
#define NJOB_RM  4096
#define NJOBS (NJOB_ENC + NJOB_DEC + NJOB_TR + NJOB_WN + NJOB_RM)

typedef __attribute__((ext_vector_type(8))) short short8v;
typedef __attribute__((ext_vector_type(4))) float f32x4;

__device__ __forceinline__ unsigned short bf16_rne(float x){
    unsigned int u = __float_as_uint(x);
    u += 0x7fffu + ((u >> 16) & 1u);
    return (unsigned short)(u >> 16);
}
__device__ __forceinline__ float bf16f(unsigned short h){
    return __uint_as_float(((unsigned int)h) << 16);
}

// ---------------- UBER kernel: 64 LSTM blocks (r10 schedule) + 192 workers ---
__global__ __launch_bounds__(512) void lstm_persist(
        float* __restrict__ Xenc, float* __restrict__ Xdec,
        const float* __restrict__ Whh_e, const float* __restrict__ Whh_d,
        unsigned int* __restrict__ h_pk,   // [2][512][32]
        float* __restrict__ hs,            // [127][32][512]
        int* __restrict__ flags,           // [64]
        int* __restrict__ decdone,         // [1]
        int* __restrict__ encdone,         // [32]
        const int* __restrict__ ids,
        const float* __restrict__ eEmb, const float* __restrict__ eWih,
        const float* __restrict__ eB,
        const float* __restrict__ dEmb, const float* __restrict__ dWih,
        const float* __restrict__ dB,
        const float* __restrict__ fcW, float* __restrict__ fcWt,
        const float* __restrict__ fcb, const int* __restrict__ mask,
        const float* __restrict__ gum, const float* __restrict__ rinit,
        float* __restrict__ Mr, unsigned int* __restrict__ scal,
        int* __restrict__ candCnt, int* __restrict__ candList,
        float* __restrict__ outp)
{
    __shared__ float smem[11392];
    const int tid = threadIdx.x;
    const int bid = blockIdx.x;

    if (bid >= NB) {
        // =============== worker blocks: grid-stride job loop ===============
        const int wid = bid - NB;
        for (int job = wid; job < NJOBS; job += NWK) {
            if (job < NJOB_ENC + NJOB_DEC) {
                // ---- enc/dec X gemm tile (128m x 128n), 512 threads ----
                const bool isenc = job < NJOB_ENC;
                const int jj = isenc ? job : job - NJOB_ENC;
                const int my = jj >> 4, nx = jj & 15;
                const int m0 = my*128, n0 = nx*128;
                const int M = isenc ? TT*BB : TD*BB;
                const float* emb = isenc ? eEmb : dEmb;
                const float* Wih = isenc ? eWih : dWih;
                const float* bv  = isenc ? eB   : dB;
                float* Xo        = isenc ? Xenc : Xdec;
                float* As = smem;              // [16][128]
                float* Bs = smem + 2048;       // [16][128]
                int* toks = (int*)(smem + 4096);
                if (tid < 128) {
                    int mr = m0 + tid, tk = 0;
                    if (mr < M) { int t = mr >> 5, b2 = mr & 31; tk = ids[b2*TT + t]; }
                    toks[tid] = tk;
                }
                __syncthreads();
                float acc[4][8] = {};
                const int ty = tid >> 4, tx = tid & 15;
                for (int kt = 0; kt < EMB; kt += 16) {
                    {
                        int row = tid >> 2, k4 = (tid & 3)*4;
                        float4 a = *(const float4*)&emb[(size_t)toks[row]*EMB + kt + k4];
                        As[(k4+0)*128+row] = a.x; As[(k4+1)*128+row] = a.y;
                        As[(k4+2)*128+row] = a.z; As[(k4+3)*128+row] = a.w;
                    }
                    {
                        int kr = tid >> 5, c4 = (tid & 31)*4;
                        *(float4*)&Bs[kr*128 + c4] =
                            *(const float4*)&Wih[(size_t)(kt+kr)*G4 + n0 + c4];
                    }
                    __syncthreads();
                    #pragma unroll
                    for (int k = 0; k < 16; k++) {
                        float a4[4], b8[8];
                        #pragma unroll
                        for (int i = 0; i < 4; i++) a4[i] = As[k*128 + ty*4+i];
                        #pragma unroll
                        for (int j = 0; j < 8; j++) b8[j] = Bs[k*128 + tx*8+j];
                        #pragma unroll
                        for (int i = 0; i < 4; i++) {
                            #pragma unroll
                            for (int j = 0; j < 8; j++)
                                acc[i][j] = fmaf(a4[i], b8[j], acc[i][j]);
                        }
                    }
                    __syncthreads();
                }
                #pragma unroll
                for (int i = 0; i < 4; i++) {
                    int mr = m0 + ty*4 + i;
                    if (mr < M) {
                        int t = mr >> 5, b2 = mr & 31;
                        #pragma unroll
                        for (int j = 0; j < 8; j++) {
                            int nc = n0 + tx*8 + j;
                            Xo[((size_t)t*G4 + nc)*BB + b2] = acc[i][j] + bv[nc];
                        }
                    }
                }
                __syncthreads();               // all stores acked
                if (tid == 0) {                // release: wbl2 + count
                    if (isenc)
                        __hip_atomic_fetch_add(&encdone[my], 1,
                            __ATOMIC_RELEASE, __HIP_MEMORY_SCOPE_AGENT);
                    else
                        __hip_atomic_fetch_add(decdone, 1,
                            __ATOMIC_RELEASE, __HIP_MEMORY_SCOPE_AGENT);
                }
            } else if (job < NJOB_ENC + NJOB_DEC + NJOB_TR) {
                // ---- fc_W transpose strip: 32 v-cols x 512 k ----
                const int v0 = (job - NJOB_ENC - NJOB_DEC)*32;
                float* tile = smem;            // [16][33]
                for (int k0 = 0; k0 < HID; k0 += 16) {
                    {
                        int kk = tid >> 5, vv = tid & 31;
                        int v = v0 + vv;
                        tile[kk*33 + vv] = (v < NV) ? fcW[(size_t)(k0+kk)*NV + v] : 0.f;
                    }
                    __syncthreads();
                    {
                        int vy = tid >> 4, kx = tid & 15;
                        int v = v0 + vy;
                        if (v < NV) fcWt[(size_t)v*HID + k0 + kx] = tile[kx*33 + vy];
                    }
                    __syncthreads();
                }
            } else if (job < NJOB_ENC + NJOB_DEC + NJOB_TR + NJOB_WN) {
                // ---- wnorm: 512 vocab cols ----
                int v = (job - NJOB_ENC - NJOB_DEC - NJOB_TR)*512 + tid;
                if (v < NV) {
                    float s = 0.f;
                    for (int k = 0; k < HID; k++) {
                        float x = fcW[(size_t)k*NV + v]; s = fmaf(x, x, s);
                    }
                    atomicMax(&scal[0], __float_as_uint(s));
                    atomicMax(&scal[1], __float_as_uint(fabsf(fcb[v])));
                }
            } else {
                // ---- row job: finalize easy rows; Mr+candidates+zero for rest
                const int row = job - NJOB_ENC - NJOB_DEC - NJOB_TR - NJOB_WN;
                const int b = row >> 7, t = row & 127;
                const int mrow = mask[row];
                float4* o = (float4*)(outp + (size_t)row*NV);
                if (mrow == 0) {
                    int win = ids[b*TT + t];
                    for (int idx = tid; idx < 2500; idx += 512) {
                        int vb = idx*4;
                        float4 val = {0.f,0.f,0.f,0.f};
                        if (win >= vb && win < vb+4) ((float*)&val)[win-vb] = 1.0f;
                        o[idx] = val;
                    }
                } else if (t == 0) {
                    const float* g  = gum   + (size_t)b*NV;
                    const float* r0 = rinit + (size_t)b*NV;
                    float bs = -1e30f; int bv2 = 0x7fffffff;
                    for (int v = tid; v < NV; v += 512) {
                        float sc = r0[v] + g[v];
                        if (sc > bs || (sc == bs && v < bv2)) { bs = sc; bv2 = v; }
                    }
                    float* red = smem;
                    int* idxr = (int*)(smem + 512);
                    red[tid] = bs; idxr[tid] = bv2; __syncthreads();
                    for (int s = 256; s; s >>= 1) {
                        if (tid < s) {
                            if (red[tid+s] > red[tid] ||
                                (red[tid+s] == red[tid] && idxr[tid+s] < idxr[tid])) {
                                red[tid] = red[tid+s]; idxr[tid] = idxr[tid+s];
                            }
                        }
                        __syncthreads();
                    }
                    int win = idxr[0];
                    __syncthreads();
                    for (int idx = tid; idx < 2500; idx += 512) {
                        int vb = idx*4;
                        float4 val = {0.f,0.f,0.f,0.f};
                        if (win >= vb && win < vb+4) ((float*)&val)[win-vb] = 1.0f;
                        o[idx] = val;
                    }
                } else {
                    int* wk   = (int*)&smem[1024];
                    int* ccnt = (int*)&smem[1040];
                    int mi = (tid < TT) ? mask[b*TT + tid] : 0;
                    unsigned long long bal = __ballot(tid < t && mi != 0);
                    if ((tid & 63) == 0) wk[tid >> 6] = __popcll(bal);
                    if (tid == 0) *ccnt = 0;
                    __syncthreads();
                    const int k = wk[0] + wk[1];
                    const float* g = gum + ((size_t)k*BB + b)*NV;
                    float m = -1e30f;
                    for (int v = tid; v < NV; v += 512) m = fmaxf(m, g[v]);
                    float* red = smem;
                    red[tid] = m; __syncthreads();
                    for (int s = 256; s; s >>= 1) {
                        if (tid < s) red[tid] = fmaxf(red[tid], red[tid+s]);
                        __syncthreads();
                    }
                    const float Mv = red[0];
                    const float thr0 = Mv - CAND_DELTA;
                    for (int v = tid; v < NV; v += 512) {
                        if (g[v] >= thr0) {
                            int pos = atomicAdd(ccnt, 1);
                            if (pos < CAND_CAP) candList[row*CAND_CAP + pos] = v;
                        }
                    }
                    float4 z = {0.f,0.f,0.f,0.f};
                    for (int idx = tid; idx < 2500; idx += 512) o[idx] = z;
                    __syncthreads();
                    if (tid == 0) { candCnt[row] = *ccnt; Mr[row] = Mv; }
                    __syncthreads();
                }
            }
        }
        return;
    }

    // =============== LSTM path: r10 schedule verbatim + encdone gating ======
    float* partials = smem;            // [8][32][36] (also W-stage scratch)
    float* xbuf     = smem + 9216;     // [2][32][33]

    const int u0  = bid*UPB;
    const int w   = tid >> 6;
    const int l   = tid & 63;
    const int rl  = l & 15;
    const int kg  = (l >> 4) * 8;
    const int r4  = (l >> 4) * 4;
    const int gb  = tid >> 3, gul = tid & 7;   // gate mapping (tid<256)

    short8v wH_n0k0, wH_n0k1, wH_n1k0, wH_n1k1;
    short8v wL_n0k0, wL_n0k1, wL_n1k0, wL_n1k1;

    #define BW(WH, WL, KB, CO) do { _Pragma("unroll") \
        for (int j = 0; j < 8; ++j) { \
            float wv2 = partials[((KB)+j)*32 + (CO) + rl]; \
            unsigned short htop = bf16_rne(wv2); \
            WH[j] = (short)htop; \
            WL[j] = (short)bf16_rne(wv2 - bf16f(htop)); \
        } } while(0)

    #define STAGE_BUILD(SRC) do { \
        for (int c = 0; c < 4; ++c) { \
            int k0 = c*128; \
            __syncthreads(); \
            for (int i = tid; i < 4096; i += 512) { \
                int kl = i >> 5, n = i & 31; \
                partials[kl*32 + n] = SRC[(size_t)(k0+kl)*G4 + (size_t)((n>>3)*512 + u0 + (n&7))]; \
            } \
            __syncthreads(); \
            if ((w >> 1) == c) { \
                int kb0 = w*64 - k0 + kg; \
                BW(wH_n0k0, wL_n0k0, kb0,      0); \
                BW(wH_n0k1, wL_n0k1, kb0 + 32, 0); \
                BW(wH_n1k0, wL_n1k0, kb0,     16); \
                BW(wH_n1k1, wL_n1k1, kb0 + 32,16); \
            } \
        } \
        __syncthreads(); } while(0)

    STAGE_BUILD(Whh_e);

    {   // prologue: wait X-group 0 produced, then stage X(0) into xbuf[0]
        while (__hip_atomic_load(&encdone[0], __ATOMIC_RELAXED,
                                 __HIP_MEMORY_SCOPE_AGENT) < 16)
            __builtin_amdgcn_s_sleep(2);
        for (int i = tid; i < 1024; i += 512) {
            int row2 = i & 31, n = i >> 5;
            xbuf[row2*33 + n] = Xenc[(size_t)((n>>3)*512 + u0 + (n&7))*32 + row2];
        }
        __syncthreads();
    }

    float c_reg = 0.f;

    #define MM6(ACC, AH0, AH1, AL0, AL1, WH0, WH1, WL0, WL1) do { \
        ACC = __builtin_amdgcn_mfma_f32_16x16x32_bf16(AH0, WH0, ACC, 0,0,0); \
        ACC = __builtin_amdgcn_mfma_f32_16x16x32_bf16(AH1, WH1, ACC, 0,0,0); \
        ACC = __builtin_amdgcn_mfma_f32_16x16x32_bf16(AL0, WH0, ACC, 0,0,0); \
        ACC = __builtin_amdgcn_mfma_f32_16x16x32_bf16(AL1, WH1, ACC, 0,0,0); \
        ACC = __builtin_amdgcn_mfma_f32_16x16x32_bf16(AH0, WL0, ACC, 0,0,0); \
        ACC = __builtin_amdgcn_mfma_f32_16x16x32_bf16(AH1, WL1, ACC, 0,0,0); \
    } while(0)

    for (int gstep = 0; gstep < NT_STEPS; ++gstep) {
        const bool enc = gstep < TT;
        const int t = enc ? gstep : gstep - TT;

        f32x4 acc00 = {0,0,0,0}, acc01 = {0,0,0,0}, acc10 = {0,0,0,0}, acc11 = {0,0,0,0};
        if (gstep > 0) {
            const unsigned int* hp = h_pk + (size_t)(gstep & 1)*16384;
            short8v aH_m0k0, aH_m0k1, aH_m1k0, aH_m1k1;
            short8v aL_m0k0, aL_m0k1, aL_m1k0, aL_m1k1;
            #define LOAD_A(AH, AL, MT, KS) do { \
                unsigned int pv[8]; \
                int kbase = w*64 + (KS)*32 + kg; \
                int brow = (MT)*16 + rl; \
                _Pragma("unroll") \
                for (int j = 0; j < 8; ++j) \
                    pv[j] = __hip_atomic_load(&hp[(kbase+j)*32 + brow], \
                                __ATOMIC_RELAXED, __HIP_MEMORY_SCOPE_AGENT); \
                _Pragma("unroll") \
                for (int j = 0; j < 8; ++j) { \
                    AH[j] = (short)(pv[j] & 0xffffu); \
                    AL[j] = (short)(pv[j] >> 16); \
                } } while(0)
            LOAD_A(aH_m0k0, aL_m0k0, 0, 0); LOAD_A(aH_m0k1, aL_m0k1, 0, 1);
            LOAD_A(aH_m1k0, aL_m1k0, 1, 0); LOAD_A(aH_m1k1, aL_m1k1, 1, 1);
            MM6(acc00, aH_m0k0, aH_m0k1, aL_m0k0, aL_m0k1, wH_n0k0, wH_n0k1, wL_n0k0, wL_n0k1);
            MM6(acc01, aH_m0k0, aH_m0k1, aL_m0k0, aL_m0k1, wH_n1k0, wH_n1k1, wL_n1k0, wL_n1k1);
            MM6(acc10, aH_m1k0, aH_m1k1, aL_m1k0, aL_m1k1, wH_n0k0, wH_n0k1, wL_n0k0, wL_n0k1);
            MM6(acc11, aH_m1k0, aH_m1k1, aL_m1k0, aL_m1k1, wH_n1k0, wH_n1k1, wL_n1k0, wL_n1k1);
        }
        #pragma unroll
        for (int j = 0; j < 4; ++j) {
            partials[(w*32 +      r4 + j)*36 +      rl] = acc00[j];
            partials[(w*32 +      r4 + j)*36 + 16 + rl] = acc01[j];
            partials[(w*32 + 16 + r4 + j)*36 +      rl] = acc10[j];
            partials[(w*32 + 16 + r4 + j)*36 + 16 + rl] = acc11[j];
        }
        __syncthreads();

        float hv = 0.f;
        if (tid < 256) {
            float pre[4];
            #pragma unroll
            for (int gg = 0; gg < 4; ++gg) {
                float s = xbuf[(gstep & 1)*1056 + gb*33 + gg*8 + gul];
                #pragma unroll
                for (int ww = 0; ww < 8; ++ww)
                    s += partials[(ww*32 + gb)*36 + gg*8 + gul];
                pre[gg] = s;
            }
            float iv = 1.f/(1.f + expf(-pre[0]));
            float fv = 1.f/(1.f + expf(-pre[1]));
            float gv = tanhf(pre[2]);
            float ov = 1.f/(1.f + expf(-pre[3]));
            c_reg = fmaf(fv, c_reg, iv*gv);
            hv = ov * tanhf(c_reg);
            unsigned short hh = bf16_rne(hv);
            unsigned short hl = bf16_rne(hv - bf16f(hh));
            unsigned int pk = (unsigned int)hh | ((unsigned int)hl << 16);
            __hip_atomic_store(&h_pk[(size_t)((gstep+1) & 1)*16384 + (u0+gul)*32 + gb],
                               pk, __ATOMIC_RELAXED, __HIP_MEMORY_SCOPE_AGENT);
        }
        __syncthreads();                   // vmcnt(0): h_pk stores at coherence pt
        if (gstep < NT_STEPS - 1 && tid == 0)
            __hip_atomic_store(&flags[bid], gstep + 1,
                               __ATOMIC_RELAXED, __HIP_MEMORY_SCOPE_AGENT);
        if (!enc && tid < 256)
            hs[((size_t)t*BB + gb)*HID + u0 + gul] = hv;
        if (gstep == NT_STEPS - 1) break;

        if (gstep == TT - 1) STAGE_BUILD(Whh_d);   // phase switch

        {   // stage X for next step (overlaps the poll wait)
            if (gstep + 1 == TT) {         // one-time decoder-X readiness guard
                if (tid == 0) {
                    while (__hip_atomic_load(decdone, __ATOMIC_RELAXED,
                                             __HIP_MEMORY_SCOPE_AGENT) < NJOB_DEC)
                        __builtin_amdgcn_s_sleep(8);
                }
                __syncthreads();
                __builtin_amdgcn_fence(__ATOMIC_ACQUIRE, "agent");
            }
            int tn = gstep + 1 < TT ? gstep + 1 : gstep + 1 - TT;
            if (gstep + 1 < TT) {          // enc-phase group readiness (cheap)
                while (__hip_atomic_load(&encdone[tn >> 2], __ATOMIC_RELAXED,
                                         __HIP_MEMORY_SCOPE_AGENT) < 16)
                    __builtin_amdgcn_s_sleep(1);
            }
            const float* Xt = (gstep + 1 < TT ? (const float*)Xenc : (const float*)Xdec)
                              + (size_t)tn*G4*BB;
            for (int i = tid; i < 1024; i += 512) {
                int row2 = i & 31, n = i >> 5;
                xbuf[((gstep+1) & 1)*1056 + row2*33 + n] =
                    Xt[(size_t)((n>>3)*512 + u0 + (n&7))*32 + row2];
            }
        }
        if (tid < NB) {
            while (__hip_atomic_load(&flags[tid], __ATOMIC_RELAXED,
                                     __HIP_MEMORY_SCOPE_AGENT) <= gstep) {}
        }
        __syncthreads();
        asm volatile("" ::: "memory");
    }
}

// ------- final: masked t>=1 rows only; candidate dots + single-elem write ----
__global__ __launch_bounds__(256) void cand_write(
        const int* __restrict__ mask, const float* __restrict__ gum,
        const float* __restrict__ hs, const float* __restrict__ Wt,
        const float* __restrict__ fcb, const float* __restrict__ Mr,
        const unsigned int* __restrict__ scal,
        const int* __restrict__ candCnt, const int* __restrict__ candList,
        float* __restrict__ out)
{
    const int row = blockIdx.x, b = row >> 7, t = row & 127;
    if (t == 0 || mask[row] == 0) return;      // handled inside uber kernel
    const int tid = threadIdx.x;
    __shared__ float red[256];
    __shared__ int list[256];
    __shared__ int wcnt[4];

    int mi = (tid < TT) ? mask[b*TT + tid] : 0;
    unsigned long long bal = __ballot(tid < t && mi != 0);
    if ((tid & 63) == 0) wcnt[tid >> 6] = __popcll(bal);
    __syncthreads();
    const int k = wcnt[0] + wcnt[1];
    __syncthreads();

    const float* g    = gum + ((size_t)k*BB + b)*NV;
    const float* hrow = hs + ((size_t)(t-1)*BB + b)*HID;
    float hn = 0.f;
    for (int k2 = tid; k2 < HID; k2 += 256) { float x = hrow[k2]; hn = fmaf(x, x, hn); }
    red[tid] = hn; __syncthreads();
    for (int s = 128; s; s >>= 1) {
        if (tid < s) red[tid] += red[tid+s];
        __syncthreads();
    }
    const float Mv = Mr[row];
    float bound = sqrtf(__uint_as_float(scal[0])) * sqrtf(red[0])
                + __uint_as_float(scal[1]);
    float thr = Mv - 2.0f*bound*1.05f - 1e-6f;
    __syncthreads();

    float curS = -1e30f; int curV = 0x7fffffff;
    const int cnt = candCnt[row];

    if (cnt <= CAND_CAP && thr >= Mv - CAND_DELTA) {
        for (int ci = 0; ci < cnt; ci++) {
            int vc = candList[row*CAND_CAP + ci];
            float p = 0.f;
            for (int k2 = tid; k2 < HID; k2 += 256)
                p = fmaf(hrow[k2], Wt[(size_t)vc*HID + k2], p);
            red[tid] = p; __syncthreads();
            for (int s = 128; s; s >>= 1) {
                if (tid < s) red[tid] += red[tid+s];
                __syncthreads();
            }
            if (tid == 0) {
                float sc = (red[0] + fcb[vc]) + g[vc];
                if (sc > curS || (sc == curS && vc < curV)) { curS = sc; curV = vc; }
            }
            __syncthreads();
        }
    } else {
        int wv = tid >> 6, lane = tid & 63;
        for (int v0 = 0; v0 < NV; v0 += 256) {
            int v = v0 + tid;
            bool ok = (v < NV) && (g[v] >= thr);
            unsigned long long mb = __ballot(ok);
            if (lane == 0) wcnt[wv] = __popcll(mb);
            __syncthreads();
            int off = 0;
            #pragma unroll
            for (int w = 0; w < 4; w++) if (w < wv) off += wcnt[w];
            int tot = wcnt[0] + wcnt[1] + wcnt[2] + wcnt[3];
            if (ok) {
                int pos = off + __popcll(mb & ((1ull << lane) - 1ull));
                list[pos] = v;
            }
            __syncthreads();
            for (int ci = 0; ci < tot; ci++) {
                int vc = list[ci];
                float p = 0.f;
                for (int k2 = tid; k2 < HID; k2 += 256)
                    p = fmaf(hrow[k2], Wt[(size_t)vc*HID + k2], p);
                red[tid] = p; __syncthreads();
                for (int s = 128; s; s >>= 1) {
                    if (tid < s) red[tid] += red[tid+s];
                    __syncthreads();
                }
                if (tid == 0) {
                    float sc = (red[0] + fcb[vc]) + g[vc];
                    if (sc > curS || (sc == curS && vc < curV)) { curS = sc; curV = vc; }
                }
                __syncthreads();
            }
        }
    }
    if (tid == 0) out[(size_t)row*NV + curV] = 1.0f;   // row pre-zeroed in uber
}

extern "C" void kernel_launch(void* const* d_in, const int* in_sizes, int n_in,
                              void* d_out, int out_size, void* d_ws, size_t ws_size,
                              hipStream_t stream)
{
    const int*   ids   = (const int*)d_in[0];
    const int*   mask  = (const int*)d_in[1];
    const float* eEmb  = (const float*)d_in[2];
    const float* eWih  = (const float*)d_in[3];
    const float* eWhh  = (const float*)d_in[4];
    const float* eB    = (const float*)d_in[5];
    const float* dEmb  = (const float*)d_in[6];
    const float* dWih  = (const float*)d_in[7];
    const float* dWhh  = (const float*)d_in[8];
    const float* dB    = (const float*)d_in[9];
    const float* fcW   = (const float*)d_in[10];
    const float* fcb   = (const float*)d_in[11];
    const float* rinit = (const float*)d_in[12];
    const float* gum   = (const float*)d_in[13];
    float* out = (float*)d_out;

    float* wsf = (float*)d_ws;
    size_t off = 0;
    float* Xenc = wsf + off; off += (size_t)TT*BB*G4;        // [t][col][b]
    float* Xdec = wsf + off; off += (size_t)TD*BB*G4;
    unsigned int* h_pk = (unsigned int*)(wsf + off); off += 2*(size_t)BB*HID;
    float* hs   = wsf + off; off += (size_t)TD*BB*HID;
    float* fcWt = wsf + off; off += (size_t)NV*HID;
    float* Mr   = wsf + off; off += 4096;
    int* candCnt  = (int*)(wsf + off); off += 4096;
    int* candList = (int*)(wsf + off); off += 4096*CAND_CAP;
    unsigned int* ctl = (unsigned int*)(wsf + off); off += 128;
    unsigned int* scal = ctl;                 // [0..7]
    int* flags    = (int*)(ctl + 8);          // [8..71]
    int* decdone  = (int*)(ctl + 72);         // [72]
    int* encdone  = (int*)(ctl + 80);         // [80..111]

    hipMemsetAsync(ctl, 0, 128*sizeof(int), stream);

    lstm_persist<<<GRID_UBER, 512, 0, stream>>>(Xenc, Xdec, eWhh, dWhh,
        h_pk, hs, flags, decdone, encdone,
        ids, eEmb, eWih, eB, dEmb, dWih, dB,
        fcW, fcWt, fcb, mask, gum, rinit,
        Mr, scal, candCnt, candList, out);

    cand_write<<<4096, 256, 0, stream>>>(mask, gum, hs, fcWt, fcb,
                                         Mr, scal, candCnt, candList, out);
}

// Round 13
// 966.279 us; speedup vs baseline: 1.6098x; 1.0591x over previous
//
#include <hip/hip_runtime.h>
#include <hip/hip_bf16.h>
#include <math.h>

#define BB 32
#define TT 128
#define TD 127
#define EMB 256
#define HID 512
#define G4 2048
#define NV 10000
#define NB 64        // lstm blocks
#define NWK 192      // worker blocks
#define GRID_UBER (NB + NWK)
#define UPB 8
#define NT_STEPS (TT + TD)
#define CAND_CAP 16
#define CAND_DELTA 1.0f

#define NJOB_DEC 512
#define NJOB_TR  313
#define NJOB_WN  20
#define NJOB_RM  4096
#define NJOBS (NJOB_DEC + NJOB_TR + NJOB_WN + NJOB_RM)

typedef __attribute__((ext_vector_type(8))) short short8v;
typedef __attribute__((ext_vector_type(4))) float f32x4;

__device__ __forceinline__ unsigned short bf16_rne(float x){
    unsigned int u = __float_as_uint(x);
    u += 0x7fffu + ((u >> 16) & 1u);
    return (unsigned short)(u >> 16);
}
__device__ __forceinline__ float bf16f(unsigned short h){
    return __uint_as_float(((unsigned int)h) << 16);
}

// ---------------- GEMM (encoder X): X[t][col][b] = embed[tok] @ W + bias ----
__global__ __launch_bounds__(256) void gemm_x(const int* __restrict__ ids,
        const float* __restrict__ embed, const float* __restrict__ W,
        const float* __restrict__ bias, float* __restrict__ X, int M)
{
    __shared__ float As[16][128];
    __shared__ float Bs[16][128];
    __shared__ int toks[128];
    const int tid = threadIdx.x;
    const int m0 = blockIdx.y * 128, n0 = blockIdx.x * 128;
    if (tid < 128) {
        int mr = m0 + tid, tk = 0;
        if (mr < M) { int t = mr >> 5, b = mr & 31; tk = ids[b*TT + t]; }
        toks[tid] = tk;
    }
    __syncthreads();
    float acc[8][8] = {};
    const int ty = tid >> 4, tx = tid & 15;
    for (int kt = 0; kt < EMB; kt += 16) {
        #pragma unroll
        for (int i = 0; i < 2; i++) {
            int idx = tid*2 + i;
            int row = idx >> 2, k4 = (idx & 3)*4;
            float4 a = *(const float4*)&embed[(size_t)toks[row]*EMB + kt + k4];
            As[k4+0][row] = a.x; As[k4+1][row] = a.y; As[k4+2][row] = a.z; As[k4+3][row] = a.w;
        }
        #pragma unroll
        for (int i = 0; i < 2; i++) {
            int idx = tid*2 + i;
            int kr = idx >> 5, c4 = (idx & 31)*4;
            *(float4*)&Bs[kr][c4] = *(const float4*)&W[(size_t)(kt+kr)*G4 + n0 + c4];
        }
        __syncthreads();
        #pragma unroll
        for (int k = 0; k < 16; k++) {
            float a8[8], b8[8];
            #pragma unroll
            for (int i = 0; i < 8; i++) a8[i] = As[k][ty*8+i];
            #pragma unroll
            for (int j = 0; j < 8; j++) b8[j] = Bs[k][tx*8+j];
            #pragma unroll
            for (int i = 0; i < 8; i++) {
                #pragma unroll
                for (int j = 0; j < 8; j++)
                    acc[i][j] = fmaf(a8[i], b8[j], acc[i][j]);
            }
        }
        __syncthreads();
    }
    #pragma unroll
    for (int i = 0; i < 8; i++) {
        int mr = m0 + ty*8 + i;
        if (mr < M) {
            int tt = mr >> 5, bb2 = mr & 31;
            #pragma unroll
            for (int j = 0; j < 8; j++) {
                int nc = n0 + tx*8 + j;
                X[((size_t)tt*G4 + nc)*BB + bb2] = acc[i][j] + bias[nc];
            }
        }
    }
}

// ---------------- UBER kernel: 64 round-5 LSTM blocks + 192 tail workers ----
__global__ __launch_bounds__(512) void lstm_persist(
        const float* __restrict__ Xenc, float* __restrict__ Xdec,
        const float* __restrict__ Whh_e, const float* __restrict__ Whh_d,
        unsigned int* __restrict__ h_pk,   // [2][512][32]
        float* __restrict__ hs,            // [127][32][512]
        int* __restrict__ flags,           // [64]
        int* __restrict__ decdone,         // [1]
        const int* __restrict__ ids, const float* __restrict__ dEmb,
        const float* __restrict__ dWih, const float* __restrict__ dB,
        const float* __restrict__ fcW, float* __restrict__ fcWt,
        const float* __restrict__ fcb, const int* __restrict__ mask,
        const float* __restrict__ gum, const float* __restrict__ rinit,
        float* __restrict__ Mr, unsigned int* __restrict__ scal,
        int* __restrict__ candCnt, int* __restrict__ candList,
        float* __restrict__ outp)
{
    __shared__ float smem[11392];
    const int tid = threadIdx.x;
    const int bid = blockIdx.x;

    if (bid >= NB) {
        // =============== worker blocks: grid-stride job loop ===============
        const int wid = bid - NB;
        for (int job = wid; job < NJOBS; job += NWK) {
            if (job < NJOB_DEC) {
                // ---- decoder-X gemm tile (128m x 128n), 512 threads ----
                const int my = job >> 4, nx = job & 15;
                const int m0 = my*128, n0 = nx*128;
                const int M = TD*BB;
                float* As = smem;              // [16][128]
                float* Bs = smem + 2048;       // [16][128]
                int* toks = (int*)(smem + 4096);
                if (tid < 128) {
                    int mr = m0 + tid, tk = 0;
                    if (mr < M) { int t = mr >> 5, b2 = mr & 31; tk = ids[b2*TT + t]; }
                    toks[tid] = tk;
                }
                __syncthreads();
                float acc[4][8] = {};
                const int ty = tid >> 4, tx = tid & 15;
                for (int kt = 0; kt < EMB; kt += 16) {
                    {
                        int row = tid >> 2, k4 = (tid & 3)*4;
                        float4 a = *(const float4*)&dEmb[(size_t)toks[row]*EMB + kt + k4];
                        As[(k4+0)*128+row] = a.x; As[(k4+1)*128+row] = a.y;
                        As[(k4+2)*128+row] = a.z; As[(k4+3)*128+row] = a.w;
                    }
                    {
                        int kr = tid >> 5, c4 = (tid & 31)*4;
                        *(float4*)&Bs[kr*128 + c4] =
                            *(const float4*)&dWih[(size_t)(kt+kr)*G4 + n0 + c4];
                    }
                    __syncthreads();
                    #pragma unroll
                    for (int k = 0; k < 16; k++) {
                        float a4[4], b8[8];
                        #pragma unroll
                        for (int i = 0; i < 4; i++) a4[i] = As[k*128 + ty*4+i];
                        #pragma unroll
                        for (int j = 0; j < 8; j++) b8[j] = Bs[k*128 + tx*8+j];
                        #pragma unroll
                        for (int i = 0; i < 4; i++) {
                            #pragma unroll
                            for (int j = 0; j < 8; j++)
                                acc[i][j] = fmaf(a4[i], b8[j], acc[i][j]);
                        }
                    }
                    __syncthreads();
                }
                #pragma unroll
                for (int i = 0; i < 4; i++) {
                    int mr = m0 + ty*4 + i;
                    if (mr < M) {
                        int t = mr >> 5, b2 = mr & 31;
                        #pragma unroll
                        for (int j = 0; j < 8; j++) {
                            int nc = n0 + tx*8 + j;
                            Xdec[((size_t)t*G4 + nc)*BB + b2] = acc[i][j] + dB[nc];
                        }
                    }
                }
                __syncthreads();               // all stores acked
                if (tid == 0)                  // release: wbl2 + count
                    __hip_atomic_fetch_add(decdone, 1,
                        __ATOMIC_RELEASE, __HIP_MEMORY_SCOPE_AGENT);
            } else if (job < NJOB_DEC + NJOB_TR) {
                // ---- fc_W transpose strip: 32 v-cols x 512 k ----
                const int v0 = (job - NJOB_DEC)*32;
                float* tile = smem;            // [16][33]
                for (int k0 = 0; k0 < HID; k0 += 16) {
                    {
                        int kk = tid >> 5, vv = tid & 31;
                        int v = v0 + vv;
                        tile[kk*33 + vv] = (v < NV) ? fcW[(size_t)(k0+kk)*NV + v] : 0.f;
                    }
                    __syncthreads();
                    {
                        int vy = tid >> 4, kx = tid & 15;
                        int v = v0 + vy;
                        if (v < NV) fcWt[(size_t)v*HID + k0 + kx] = tile[kx*33 + vy];
                    }
                    __syncthreads();
                }
            } else if (job < NJOB_DEC + NJOB_TR + NJOB_WN) {
                // ---- wnorm: 512 vocab cols ----
                int v = (job - NJOB_DEC - NJOB_TR)*512 + tid;
                if (v < NV) {
                    float s = 0.f;
                    for (int k = 0; k < HID; k++) {
                        float x = fcW[(size_t)k*NV + v]; s = fmaf(x, x, s);
                    }
                    atomicMax(&scal[0], __float_as_uint(s));
                    atomicMax(&scal[1], __float_as_uint(fabsf(fcb[v])));
                }
            } else {
                // ---- row job: finalize easy rows; Mr+candidates+zero for rest
                const int row = job - NJOB_DEC - NJOB_TR - NJOB_WN;
                const int b = row >> 7, t = row & 127;
                const int mrow = mask[row];
                float4* o = (float4*)(outp + (size_t)row*NV);
                if (mrow == 0) {
                    int win = ids[b*TT + t];
                    for (int idx = tid; idx < 2500; idx += 512) {
                        int vb = idx*4;
                        float4 val = {0.f,0.f,0.f,0.f};
                        if (win >= vb && win < vb+4) ((float*)&val)[win-vb] = 1.0f;
                        o[idx] = val;
                    }
                } else if (t == 0) {
                    const float* g  = gum   + (size_t)b*NV;
                    const float* r0 = rinit + (size_t)b*NV;
                    float bs = -1e30f; int bv = 0x7fffffff;
                    for (int v = tid; v < NV; v += 512) {
                        float sc = r0[v] + g[v];
                        if (sc > bs || (sc == bs && v < bv)) { bs = sc; bv = v; }
                    }
                    float* red = smem;
                    int* idxr = (int*)(smem + 512);
                    red[tid] = bs; idxr[tid] = bv; __syncthreads();
                    for (int s = 256; s; s >>= 1) {
                        if (tid < s) {
                            if (red[tid+s] > red[tid] ||
                                (red[tid+s] == red[tid] && idxr[tid+s] < idxr[tid])) {
                                red[tid] = red[tid+s]; idxr[tid] = idxr[tid+s];
                            }
                        }
                        __syncthreads();
                    }
                    int win = idxr[0];
                    __syncthreads();
                    for (int idx = tid; idx < 2500; idx += 512) {
                        int vb = idx*4;
                        float4 val = {0.f,0.f,0.f,0.f};
                        if (win >= vb && win < vb+4) ((float*)&val)[win-vb] = 1.0f;
                        o[idx] = val;
                    }
                } else {
                    int* wk   = (int*)&smem[1024];
                    int* ccnt = (int*)&smem[1040];
                    int mi = (tid < TT) ? mask[b*TT + tid] : 0;
                    unsigned long long bal = __ballot(tid < t && mi != 0);
                    if ((tid & 63) == 0) wk[tid >> 6] = __popcll(bal);
                    if (tid == 0) *ccnt = 0;
                    __syncthreads();
                    const int k = wk[0] + wk[1];
                    const float* g = gum + ((size_t)k*BB + b)*NV;
                    float m = -1e30f;
                    for (int v = tid; v < NV; v += 512) m = fmaxf(m, g[v]);
                    float* red = smem;
                    red[tid] = m; __syncthreads();
                    for (int s = 256; s; s >>= 1) {
                        if (tid < s) red[tid] = fmaxf(red[tid], red[tid+s]);
                        __syncthreads();
                    }
                    const float Mv = red[0];
                    const float thr0 = Mv - CAND_DELTA;
                    for (int v = tid; v < NV; v += 512) {
                        if (g[v] >= thr0) {
                            int pos = atomicAdd(ccnt, 1);
                            if (pos < CAND_CAP) candList[row*CAND_CAP + pos] = v;
                        }
                    }
                    float4 z = {0.f,0.f,0.f,0.f};
                    for (int idx = tid; idx < 2500; idx += 512) o[idx] = z;
                    __syncthreads();
                    if (tid == 0) { candCnt[row] = *ccnt; Mr[row] = Mv; }
                    __syncthreads();
                }
            }
        }
        return;
    }

    // =============== round-5 LSTM path (proven fabric, unchanged) ===============
    float* partials = smem;            // [8][32][36] (also W-stage scratch)
    float* xbuf     = smem + 9216;     // [2][32][33]

    const int u0  = bid*UPB;
    const int w   = tid >> 6;
    const int l   = tid & 63;
    const int rl  = l & 15;
    const int kg  = (l >> 4) * 8;
    const int r4  = (l >> 4) * 4;
    const int gb  = tid >> 3, gul = tid & 7;   // gate mapping (tid<256)

    short8v wH_n0k0, wH_n0k1, wH_n1k0, wH_n1k1;
    short8v wL_n0k0, wL_n0k1, wL_n1k0, wL_n1k1;

    #define BW(WH, WL, KB, CO) do { _Pragma("unroll") \
        for (int j = 0; j < 8; ++j) { \
            float wv2 = partials[((KB)+j)*32 + (CO) + rl]; \
            unsigned short htop = bf16_rne(wv2); \
            WH[j] = (short)htop; \
            WL[j] = (short)bf16_rne(wv2 - bf16f(htop)); \
        } } while(0)

    #define STAGE_BUILD(SRC) do { \
        for (int c = 0; c < 4; ++c) { \
            int k0 = c*128; \
            __syncthreads(); \
            for (int i = tid; i < 4096; i += 512) { \
                int kl = i >> 5, n = i & 31; \
                partials[kl*32 + n] = SRC[(size_t)(k0+kl)*G4 + (size_t)((n>>3)*512 + u0 + (n&7))]; \
            } \
            __syncthreads(); \
            if ((w >> 1) == c) { \
                int kb0 = w*64 - k0 + kg; \
                BW(wH_n0k0, wL_n0k0, kb0,      0); \
                BW(wH_n0k1, wL_n0k1, kb0 + 32, 0); \
                BW(wH_n1k0, wL_n1k0, kb0,     16); \
                BW(wH_n1k1, wL_n1k1, kb0 + 32,16); \
            } \
        } \
        __syncthreads(); } while(0)

    STAGE_BUILD(Whh_e);

    {   // prologue: stage X(0) into xbuf[0]
        for (int i = tid; i < 1024; i += 512) {
            int row2 = i & 31, n = i >> 5;
            xbuf[row2*33 + n] = Xenc[(size_t)((n>>3)*512 + u0 + (n&7))*32 + row2];
        }
        __syncthreads();
    }

    float c_reg = 0.f;

    #define MM6(ACC, AH0, AH1, AL0, AL1, WH0, WH1, WL0, WL1) do { \
        ACC = __builtin_amdgcn_mfma_f32_16x16x32_bf16(AH0, WH0, ACC, 0,0,0); \
        ACC = __builtin_amdgcn_mfma_f32_16x16x32_bf16(AH1, WH1, ACC, 0,0,0); \
        ACC = __builtin_amdgcn_mfma_f32_16x16x32_bf16(AL0, WH0, ACC, 0,0,0); \
        ACC = __builtin_amdgcn_mfma_f32_16x16x32_bf16(AL1, WH1, ACC, 0,0,0); \
        ACC = __builtin_amdgcn_mfma_f32_16x16x32_bf16(AH0, WL0, ACC, 0,0,0); \
        ACC = __builtin_amdgcn_mfma_f32_16x16x32_bf16(AH1, WL1, ACC, 0,0,0); \
    } while(0)

    for (int gstep = 0; gstep < NT_STEPS; ++gstep) {
        const bool enc = gstep < TT;
        const int t = enc ? gstep : gstep - TT;

        f32x4 acc00 = {0,0,0,0}, acc01 = {0,0,0,0}, acc10 = {0,0,0,0}, acc11 = {0,0,0,0};
        if (gstep > 0) {
            const unsigned int* hp = h_pk + (size_t)(gstep & 1)*16384;
            short8v aH_m0k0, aH_m0k1, aH_m1k0, aH_m1k1;
            short8v aL_m0k0, aL_m0k1, aL_m1k0, aL_m1k1;
            #define LOAD_A(AH, AL, MT, KS) do { \
                unsigned int pv[8]; \
                int kbase = w*64 + (KS)*32 + kg; \
                int brow = (MT)*16 + rl; \
                _Pragma("unroll") \
                for (int j = 0; j < 8; ++j) \
                    pv[j] = __hip_atomic_load(&hp[(kbase+j)*32 + brow], \
                                __ATOMIC_RELAXED, __HIP_MEMORY_SCOPE_AGENT); \
                _Pragma("unroll") \
                for (int j = 0; j < 8; ++j) { \
                    AH[j] = (short)(pv[j] & 0xffffu); \
                    AL[j] = (short)(pv[j] >> 16); \
                } } while(0)
            LOAD_A(aH_m0k0, aL_m0k0, 0, 0); LOAD_A(aH_m0k1, aL_m0k1, 0, 1);
            LOAD_A(aH_m1k0, aL_m1k0, 1, 0); LOAD_A(aH_m1k1, aL_m1k1, 1, 1);
            MM6(acc00, aH_m0k0, aH_m0k1, aL_m0k0, aL_m0k1, wH_n0k0, wH_n0k1, wL_n0k0, wL_n0k1);
            MM6(acc01, aH_m0k0, aH_m0k1, aL_m0k0, aL_m0k1, wH_n1k0, wH_n1k1, wL_n1k0, wL_n1k1);
            MM6(acc10, aH_m1k0, aH_m1k1, aL_m1k0, aL_m1k1, wH_n0k0, wH_n0k1, wL_n0k0, wL_n0k1);
            MM6(acc11, aH_m1k0, aH_m1k1, aL_m1k0, aL_m1k1, wH_n1k0, wH_n1k1, wL_n1k0, wL_n1k1);
        }
        #pragma unroll
        for (int j = 0; j < 4; ++j) {
            partials[(w*32 +      r4 + j)*36 +      rl] = acc00[j];
            partials[(w*32 +      r4 + j)*36 + 16 + rl] = acc01[j];
            partials[(w*32 + 16 + r4 + j)*36 +      rl] = acc10[j];
            partials[(w*32 + 16 + r4 + j)*36 + 16 + rl] = acc11[j];
        }
        __syncthreads();

        float hv = 0.f;
        if (tid < 256) {
            float pre[4];
            #pragma unroll
            for (int gg = 0; gg < 4; ++gg) {
                float s = xbuf[(gstep & 1)*1056 + gb*33 + gg*8 + gul];
                #pragma unroll
                for (int ww = 0; ww < 8; ++ww)
                    s += partials[(ww*32 + gb)*36 + gg*8 + gul];
                pre[gg] = s;
            }
            float iv = 1.f/(1.f + expf(-pre[0]));
            float fv = 1.f/(1.f + expf(-pre[1]));
            float gv = tanhf(pre[2]);
            float ov = 1.f/(1.f + expf(-pre[3]));
            c_reg = fmaf(fv, c_reg, iv*gv);
            hv = ov * tanhf(c_reg);
            unsigned short hh = bf16_rne(hv);
            unsigned short hl = bf16_rne(hv - bf16f(hh));
            unsigned int pk = (unsigned int)hh | ((unsigned int)hl << 16);
            __hip_atomic_store(&h_pk[(size_t)((gstep+1) & 1)*16384 + (u0+gul)*32 + gb],
                               pk, __ATOMIC_RELAXED, __HIP_MEMORY_SCOPE_AGENT);
        }
        __syncthreads();                   // vmcnt(0): h_pk stores at coherence pt
        if (gstep < NT_STEPS - 1 && tid == 0)
            __hip_atomic_store(&flags[bid], gstep + 1,
                               __ATOMIC_RELAXED, __HIP_MEMORY_SCOPE_AGENT);
        if (!enc && tid < 256)
            hs[((size_t)t*BB + gb)*HID + u0 + gul] = hv;
        if (gstep == NT_STEPS - 1) break;

        if (gstep == TT - 1) STAGE_BUILD(Whh_d);   // phase switch

        {   // stage X for next step (overlaps the poll wait)
            if (gstep + 1 == TT) {         // one-time decoder-X readiness guard
                if (tid == 0) {
                    while (__hip_atomic_load(decdone, __ATOMIC_RELAXED,
                                             __HIP_MEMORY_SCOPE_AGENT) < NJOB_DEC)
                        __builtin_amdgcn_s_sleep(8);
                }
                __syncthreads();
                __builtin_amdgcn_fence(__ATOMIC_ACQUIRE, "agent");
            }
            int tn = gstep + 1 < TT ? gstep + 1 : gstep + 1 - TT;
            const float* Xt = (gstep + 1 < TT ? Xenc : (const float*)Xdec) + (size_t)tn*G4*BB;
            for (int i = tid; i < 1024; i += 512) {
                int row2 = i & 31, n = i >> 5;
                xbuf[((gstep+1) & 1)*1056 + row2*33 + n] =
                    Xt[(size_t)((n>>3)*512 + u0 + (n&7))*32 + row2];
            }
        }
        if (tid < NB) {
            while (__hip_atomic_load(&flags[tid], __ATOMIC_RELAXED,
                                     __HIP_MEMORY_SCOPE_AGENT) <= gstep) {}
        }
        __syncthreads();
        asm volatile("" ::: "memory");
    }
}

// ------- final: masked t>=1 rows only; candidate dots + single-elem write ----
__global__ __launch_bounds__(256) void cand_write(
        const int* __restrict__ mask, const float* __restrict__ gum,
        const float* __restrict__ hs, const float* __restrict__ Wt,
        const float* __restrict__ fcb, const float* __restrict__ Mr,
        const unsigned int* __restrict__ scal,
        const int* __restrict__ candCnt, const int* __restrict__ candList,
        float* __restrict__ out)
{
    const int row = blockIdx.x, b = row >> 7, t = row & 127;
    if (t == 0 || mask[row] == 0) return;      // handled inside uber kernel
    const int tid = threadIdx.x;
    __shared__ float red[256];
    __shared__ int list[256];
    __shared__ int wcnt[4];

    int mi = (tid < TT) ? mask[b*TT + tid] : 0;
    unsigned long long bal = __ballot(tid < t && mi != 0);
    if ((tid & 63) == 0) wcnt[tid >> 6] = __popcll(bal);
    __syncthreads();
    const int k = wcnt[0] + wcnt[1];
    __syncthreads();

    const float* g    = gum + ((size_t)k*BB + b)*NV;
    const float* hrow = hs + ((size_t)(t-1)*BB + b)*HID;
    float hn = 0.f;
    for (int k2 = tid; k2 < HID; k2 += 256) { float x = hrow[k2]; hn = fmaf(x, x, hn); }
    red[tid] = hn; __syncthreads();
    for (int s = 128; s; s >>= 1) {
        if (tid < s) red[tid] += red[tid+s];
        __syncthreads();
    }
    const float Mv = Mr[row];
    float bound = sqrtf(__uint_as_float(scal[0])) * sqrtf(red[0])
                + __uint_as_float(scal[1]);
    float thr = Mv - 2.0f*bound*1.05f - 1e-6f;
    __syncthreads();

    float curS = -1e30f; int curV = 0x7fffffff;
    const int cnt = candCnt[row];

    if (cnt <= CAND_CAP && thr >= Mv - CAND_DELTA) {
        for (int ci = 0; ci < cnt; ci++) {
            int vc = candList[row*CAND_CAP + ci];
            float p = 0.f;
            for (int k2 = tid; k2 < HID; k2 += 256)
                p = fmaf(hrow[k2], Wt[(size_t)vc*HID + k2], p);
            red[tid] = p; __syncthreads();
            for (int s = 128; s; s >>= 1) {
                if (tid < s) red[tid] += red[tid+s];
                __syncthreads();
            }
            if (tid == 0) {
                float sc = (red[0] + fcb[vc]) + g[vc];
                if (sc > curS || (sc == curS && vc < curV)) { curS = sc; curV = vc; }
            }
            __syncthreads();
        }
    } else {
        int wv = tid >> 6, lane = tid & 63;
        for (int v0 = 0; v0 < NV; v0 += 256) {
            int v = v0 + tid;
            bool ok = (v < NV) && (g[v] >= thr);
            unsigned long long mb = __ballot(ok);
            if (lane == 0) wcnt[wv] = __popcll(mb);
            __syncthreads();
            int off = 0;
            #pragma unroll
            for (int w = 0; w < 4; w++) if (w < wv) off += wcnt[w];
            int tot = wcnt[0] + wcnt[1] + wcnt[2] + wcnt[3];
            if (ok) {
                int pos = off + __popcll(mb & ((1ull << lane) - 1ull));
                list[pos] = v;
            }
            __syncthreads();
            for (int ci = 0; ci < tot; ci++) {
                int vc = list[ci];
                float p = 0.f;
                for (int k2 = tid; k2 < HID; k2 += 256)
                    p = fmaf(hrow[k2], Wt[(size_t)vc*HID + k2], p);
                red[tid] = p; __syncthreads();
                for (int s = 128; s; s >>= 1) {
                    if (tid < s) red[tid] += red[tid+s];
                    __syncthreads();
                }
                if (tid == 0) {
                    float sc = (red[0] + fcb[vc]) + g[vc];
                    if (sc > curS || (sc == curS && vc < curV)) { curS = sc; curV = vc; }
                }
                __syncthreads();
            }
        }
    }
    if (tid == 0) out[(size_t)row*NV + curV] = 1.0f;   // row pre-zeroed in uber
}

extern "C" void kernel_launch(void* const* d_in, const int* in_sizes, int n_in,
                              void* d_out, int out_size, void* d_ws, size_t ws_size,
                              hipStream_t stream)
{
    const int*   ids   = (const int*)d_in[0];
    const int*   mask  = (const int*)d_in[1];
    const float* eEmb  = (const float*)d_in[2];
    const float* eWih  = (const float*)d_in[3];
    const float* eWhh  = (const float*)d_in[4];
    const float* eB    = (const float*)d_in[5];
    const float* dEmb  = (const float*)d_in[6];
    const float* dWih  = (const float*)d_in[7];
    const float* dWhh  = (const float*)d_in[8];
    const float* dB    = (const float*)d_in[9];
    const float* fcW   = (const float*)d_in[10];
    const float* fcb   = (const float*)d_in[11];
    const float* rinit = (const float*)d_in[12];
    const float* gum   = (const float*)d_in[13];
    float* out = (float*)d_out;

    float* wsf = (float*)d_ws;
    size_t off = 0;
    float* Xenc = wsf + off; off += (size_t)TT*BB*G4;        // [t][col][b]
    float* Xdec = wsf + off; off += (size_t)TD*BB*G4;
    unsigned int* h_pk = (unsigned int*)(wsf + off); off += 2*(size_t)BB*HID;
    float* hs   = wsf + off; off += (size_t)TD*BB*HID;
    float* fcWt = wsf + off; off += (size_t)NV*HID;
    float* Mr   = wsf + off; off += 4096;
    int* candCnt  = (int*)(wsf + off); off += 4096;
    int* candList = (int*)(wsf + off); off += 4096*CAND_CAP;
    unsigned int* ctl = (unsigned int*)(wsf + off); off += 128;
    unsigned int* scal = ctl;                 // [0..7]
    int* flags   = (int*)(ctl + 8);           // [8..71]
    int* decdone = (int*)(ctl + 72);          // [72]

    hipMemsetAsync(ctl, 0, 128*sizeof(int), stream);

    dim3 gblk(16, 32);
    gemm_x<<<gblk, 256, 0, stream>>>(ids, eEmb, eWih, eB, Xenc, TT*BB);

    lstm_persist<<<GRID_UBER, 512, 0, stream>>>(Xenc, Xdec, eWhh, dWhh,
        h_pk, hs, flags, decdone,
        ids, dEmb, dWih, dB, fcW, fcWt, fcb, mask, gum, rinit,
        Mr, scal, candCnt, candList, out);

    cand_write<<<4096, 256, 0, stream>>>(mask, gum, hs, fcWt, fcb,
                                         Mr, scal, candCnt, candList, out);
}